// Round 3
// baseline (979.204 us; speedup 1.0000x reference)
//
#include <hip/hip_runtime.h>
#include <hip/hip_bf16.h>
#include <stdint.h>
#include <stddef.h>

#ifndef PARTITIONABLE
#define PARTITIONABLE 1
#endif

typedef __attribute__((ext_vector_type(8))) short short8;
typedef __attribute__((ext_vector_type(4))) float f32x4;

// ---------------- threefry2x32 (exact JAX) ----------------
__host__ __device__ __forceinline__ uint32_t rotl32(uint32_t x, int d){ return (x<<d)|(x>>(32-d)); }

__host__ __device__ __forceinline__ void tf4(uint32_t&x0, uint32_t&x1, int r0,int r1,int r2,int r3){
  x0+=x1; x1=rotl32(x1,r0); x1^=x0;
  x0+=x1; x1=rotl32(x1,r1); x1^=x0;
  x0+=x1; x1=rotl32(x1,r2); x1^=x0;
  x0+=x1; x1=rotl32(x1,r3); x1^=x0;
}
__host__ __device__ __forceinline__ void threefry2x32(uint32_t k0,uint32_t k1,uint32_t x0,uint32_t x1,
                                                      uint32_t&y0,uint32_t&y1){
  uint32_t ks2 = k0^k1^0x1BD11BDAu;
  x0+=k0; x1+=k1;
  tf4(x0,x1,13,15,26,6);  x0+=k1;  x1+=ks2+1u;
  tf4(x0,x1,17,29,16,24); x0+=ks2; x1+=k0+2u;
  tf4(x0,x1,13,15,26,6);  x0+=k0;  x1+=k1+3u;
  tf4(x0,x1,17,29,16,24); x0+=k1;  x1+=ks2+4u;
  tf4(x0,x1,13,15,26,6);  x0+=ks2; x1+=k0+5u;
  y0=x0; y1=x1;
}

__device__ __forceinline__ uint32_t random_bits32(uint32_t k0,uint32_t k1,uint32_t idx, uint32_t half){
#if PARTITIONABLE
  uint32_t y0,y1; threefry2x32(k0,k1, 0u, idx, y0,y1);
  (void)half;
  return y0 ^ y1;
#else
  uint32_t y0,y1;
  if (idx < half) { threefry2x32(k0,k1, idx, idx+half, y0,y1); return y0; }
  else            { threefry2x32(k0,k1, idx-half, idx, y0,y1); return y1; }
#endif
}

// ---------------- bf16 split helpers ----------------
__device__ __forceinline__ unsigned short bf16_rne(float x){
  unsigned u = __float_as_uint(x);
  unsigned r = (u + 0x7FFFu + ((u>>16)&1u)) >> 16;
  return (unsigned short)r;
}
__device__ __forceinline__ float bf16_tof(unsigned short h){
  return __uint_as_float(((unsigned)h)<<16);
}
__device__ __forceinline__ void split8(const float* src, short8& hi, short8& lo){
  #pragma unroll
  for (int e=0;e<8;e++){
    unsigned short h = bf16_rne(src[e]);
    hi[e] = (short)h;
    lo[e] = (short)bf16_rne(src[e] - bf16_tof(h));
  }
}

// ---------------- Markidis split-2 GEMM core: 128x256 tile, 512 threads ----------------
// A tile base pre-offset to tile row 0 (lda = row stride); B base pre-offset to col 0 of
// the 256-col window (ldb = row stride). K%32==0. acc layout: row = wr*64+i*16+(l>>4)*4+reg,
// col = wc*64+j*16+(l&15), with wr=wv>>2, wc=wv&3.
// Per-(row,col) accumulation order: k0 steps of 32; per step (hh, ah*bl, al*bh) — bit-stable.
__device__ __forceinline__ void mk_gemm(const float* __restrict__ A, int lda,
                                        const float* __restrict__ B, int ldb,
                                        int K,
                                        unsigned short* Ahi, unsigned short* Alo,
                                        unsigned short* Bhi, unsigned short* Blo,
                                        f32x4 (&acc)[4][4]){
  const int tid = threadIdx.x;
  const int lane = tid & 63;
  const int wv = tid >> 6;            // 0..7
  const int wr = wv >> 2, wc = wv & 3;
  const int arow = tid >> 2, aseg = tid & 3;   // 128 rows x 4 segs of 8 k
  const int bcol = tid & 255, bkh = tid >> 8;  // 256 cols x 2 halves of 16 k
  const int swA = (arow >> 1) & 3;
  const int swB = (bcol >> 1) & 3;

  for (int k0 = 0; k0 < K; k0 += 32){
    // A: 8 contiguous f32
    const float* pa = A + (size_t)arow*lda + k0 + aseg*8;
    float af[8];
    { float4 v0 = *(const float4*)pa; float4 v1 = *(const float4*)(pa+4);
      af[0]=v0.x; af[1]=v0.y; af[2]=v0.z; af[3]=v0.w;
      af[4]=v1.x; af[5]=v1.y; af[6]=v1.z; af[7]=v1.w; }
    // B: 16 f32 down a column (coalesced across lanes per instruction)
    float bf[16];
    const float* pb = B + (size_t)(k0 + bkh*16)*ldb + bcol;
    #pragma unroll
    for (int j=0;j<16;j++) bf[j] = pb[(size_t)j*ldb];

    { short8 vh, vl; split8(af, vh, vl);
      const int s = (aseg ^ swA)*8;
      *(short8*)&Ahi[arow*32 + s] = vh;
      *(short8*)&Alo[arow*32 + s] = vl; }
    { short8 h0,l0,h1,l1; split8(bf, h0, l0); split8(bf+8, h1, l1);
      const int s0 = ((bkh*2+0)^swB)*8, s1 = ((bkh*2+1)^swB)*8;
      *(short8*)&Bhi[bcol*32 + s0] = h0;
      *(short8*)&Bhi[bcol*32 + s1] = h1;
      *(short8*)&Blo[bcol*32 + s0] = l0;
      *(short8*)&Blo[bcol*32 + s1] = l1; }
    __syncthreads();

    short8 ah[4], al[4], bh[4], bl[4];
    const int kg = lane >> 4;
    #pragma unroll
    for (int i=0;i<4;i++){
      const int r = wr*64 + i*16 + (lane&15);
      const int offA = r*32 + ((kg ^ ((r>>1)&3))*8);
      ah[i] = *(const short8*)&Ahi[offA];
      al[i] = *(const short8*)&Alo[offA];
      const int c = wc*64 + i*16 + (lane&15);
      const int offB = c*32 + ((kg ^ ((c>>1)&3))*8);
      bh[i] = *(const short8*)&Bhi[offB];
      bl[i] = *(const short8*)&Blo[offB];
    }
    #pragma unroll
    for (int i=0;i<4;i++)
      #pragma unroll
      for (int j=0;j<4;j++){
        acc[i][j] = __builtin_amdgcn_mfma_f32_16x16x32_bf16(ah[i], bh[j], acc[i][j], 0,0,0);
        acc[i][j] = __builtin_amdgcn_mfma_f32_16x16x32_bf16(ah[i], bl[j], acc[i][j], 0,0,0);
        acc[i][j] = __builtin_amdgcn_mfma_f32_16x16x32_bf16(al[i], bh[j], acc[i][j], 0,0,0);
      }
    __syncthreads();
  }
}

// ---------------- proj + rownorm fused: Hn = normalize(h_in @ proj_w + proj_b) ----------------
__global__ __launch_bounds__(512) void proj_norm_kernel(
    const float* __restrict__ A, const float* __restrict__ B,
    const float* __restrict__ bias, float* __restrict__ Hn, int K){
  __shared__ unsigned short Ahi[4096], Alo[4096], Bhi[8192], Blo[8192];
  __shared__ float ns[4][128];
  f32x4 acc[4][4];
  #pragma unroll
  for (int i=0;i<4;i++)
    #pragma unroll
    for (int j=0;j<4;j++) acc[i][j] = (f32x4){0.f,0.f,0.f,0.f};
  const int bm = blockIdx.x * 128;
  mk_gemm(A + (size_t)bm*K, K, B, 256, K, Ahi, Alo, Bhi, Blo, acc);

  const int tid = threadIdx.x, lane = tid&63, wv = tid>>6;
  const int wr = wv>>2, wc = wv&3;
  #pragma unroll
  for (int j=0;j<4;j++){
    const int c = wc*64 + j*16 + (lane&15);
    const float bb = bias[c];
    #pragma unroll
    for (int i=0;i<4;i++)
      #pragma unroll
      for (int reg=0;reg<4;reg++) acc[i][j][reg] += bb;
  }
  // row sum of squares
  #pragma unroll
  for (int i=0;i<4;i++)
    #pragma unroll
    for (int reg=0;reg<4;reg++){
      float p = acc[i][0][reg]*acc[i][0][reg] + acc[i][1][reg]*acc[i][1][reg]
              + acc[i][2][reg]*acc[i][2][reg] + acc[i][3][reg]*acc[i][3][reg];
      #pragma unroll
      for (int o=1;o<16;o<<=1) p += __shfl_xor(p, o);
      if ((lane&15)==0) ns[wc][wr*64 + i*16 + (lane>>4)*4 + reg] = p;
    }
  __syncthreads();
  #pragma unroll
  for (int i=0;i<4;i++){
    const int rl = wr*64 + i*16 + (lane>>4)*4;
    #pragma unroll
    for (int reg=0;reg<4;reg++){
      const int r = rl + reg;
      const float tot = ns[0][r]+ns[1][r]+ns[2][r]+ns[3][r];
      const float inv = 1.0f/(sqrtf(tot)+1e-6f);
      const size_t grow = (size_t)(bm + r);
      #pragma unroll
      for (int j=0;j<4;j++){
        const int c = wc*64 + j*16 + (lane&15);
        Hn[grow*256 + c] = acc[i][j][reg]*inv;
      }
    }
  }
}

// ---------------- sim GEMM + softmax + gumbel-argmax + select + outputs, fused ----------------
__global__ __launch_bounds__(512) void sim_sample_kernel(
    const float* __restrict__ Hn, const float* __restrict__ embedT,
    const float* __restrict__ embed, const float* __restrict__ temp,
    float* __restrict__ probs, float* __restrict__ codef,
    float* __restrict__ quant, float* __restrict__ norms,
    uint32_t kc0, uint32_t kc1, uint32_t kp0, uint32_t kp1){
  __shared__ unsigned short Ahi[4096], Alo[4096], Bhi[8192], Blo[8192];
  __shared__ float redf[4][128];
  __shared__ int   redi[4][128];
  __shared__ float smax[128], ssum[128], ssel[128];
  __shared__ int   scode[128];
  f32x4 acc[4][4];
  #pragma unroll
  for (int i=0;i<4;i++)
    #pragma unroll
    for (int j=0;j<4;j++) acc[i][j] = (f32x4){0.f,0.f,0.f,0.f};
  const int bm = blockIdx.x * 128;
  mk_gemm(Hn + (size_t)bm*256, 256, embedT, 256, 256, Ahi, Alo, Bhi, Blo, acc);

  const int tid = threadIdx.x, lane = tid&63, wv = tid>>6;
  const int wr = wv>>2, wc = wv&3;
  const float tv = temp[0];
  const float alpha = 1.0f/(tv*tv);
  // transform sim -> L in place (exact round-2 arithmetic)
  #pragma unroll
  for (int i=0;i<4;i++)
    #pragma unroll
    for (int j=0;j<4;j++)
      #pragma unroll
      for (int reg=0;reg<4;reg++){
        const float s = acc[i][j][reg];
        const float dist = -2.0f*(alpha-1.0f)*s - 2.0f*s;
        acc[i][j][reg] = -dist;
      }
  // (a) row max
  #pragma unroll
  for (int i=0;i<4;i++)
    #pragma unroll
    for (int reg=0;reg<4;reg++){
      float m = fmaxf(fmaxf(acc[i][0][reg], acc[i][1][reg]),
                      fmaxf(acc[i][2][reg], acc[i][3][reg]));
      #pragma unroll
      for (int o=1;o<16;o<<=1) m = fmaxf(m, __shfl_xor(m, o));
      if ((lane&15)==0) redf[wc][wr*64 + i*16 + (lane>>4)*4 + reg] = m;
    }
  __syncthreads();
  if (tid < 128)
    smax[tid] = fmaxf(fmaxf(redf[0][tid], redf[1][tid]), fmaxf(redf[2][tid], redf[3][tid]));
  __syncthreads();
  // (c) exp-sum
  #pragma unroll
  for (int i=0;i<4;i++)
    #pragma unroll
    for (int reg=0;reg<4;reg++){
      const int r = wr*64 + i*16 + (lane>>4)*4 + reg;
      const float m = smax[r];
      float p = expf(acc[i][0][reg]-m) + expf(acc[i][1][reg]-m)
              + expf(acc[i][2][reg]-m) + expf(acc[i][3][reg]-m);
      #pragma unroll
      for (int o=1;o<16;o<<=1) p += __shfl_xor(p, o);
      if ((lane&15)==0) redf[wc][r] = p;
    }
  __syncthreads();
  if (tid < 128){
    ssum[tid] = redf[0][tid]+redf[1][tid]+redf[2][tid]+redf[3][tid];
    const uint32_t pb = random_bits32(kp0,kp1,(uint32_t)(bm+tid), 16384u);
    const float pf = __uint_as_float((pb>>9) | 0x3f800000u) - 1.0f;
    ssel[tid] = (pf > 0.0f) ? 1.0f : 0.0f;
  }
  __syncthreads();
  // (e) gumbel argmax
  #pragma unroll
  for (int i=0;i<4;i++)
    #pragma unroll
    for (int reg=0;reg<4;reg++){
      const int r = wr*64 + i*16 + (lane>>4)*4 + reg;
      const uint32_t grow = (uint32_t)(bm + r);
      float zb = -1e38f; int ib = 0x7fffffff;
      #pragma unroll
      for (int j=0;j<4;j++){
        const int c = wc*64 + j*16 + (lane&15);
        const uint32_t bits = random_bits32(kc0,kc1, grow*256u + (uint32_t)c, 4194304u);
        const float f = __uint_as_float((bits>>9) | 0x3f800000u) - 1.0f;
        const float TINY = 1.17549435082228751e-38f;
        const float u = fmaxf(TINY, f + TINY);
        const float g = -logf(-logf(u));
        const float z = acc[i][j][reg] + g;
        if (z > zb || (z == zb && c < ib)){ zb = z; ib = c; }
      }
      #pragma unroll
      for (int o=1;o<16;o<<=1){
        const float zo = __shfl_xor(zb, o); const int io = __shfl_xor(ib, o);
        if (zo > zb || (zo == zb && io < ib)){ zb = zo; ib = io; }
      }
      if ((lane&15)==0){ redf[wc][r] = zb; redi[wc][r] = ib; }
    }
  __syncthreads();
  if (tid < 128){
    float zb = redf[0][tid]; int ib = redi[0][tid];
    #pragma unroll
    for (int w=1; w<4; w++)
      if (redf[w][tid] > zb || (redf[w][tid] == zb && redi[w][tid] < ib)){
        zb = redf[w][tid]; ib = redi[w][tid];
      }
    scode[tid] = ib;
  }
  __syncthreads();
  // (g) outputs + ||embed[code]-h|| partials
  #pragma unroll
  for (int i=0;i<4;i++)
    #pragma unroll
    for (int reg=0;reg<4;reg++){
      const int r = wr*64 + i*16 + (lane>>4)*4 + reg;
      const size_t grow = (size_t)(bm + r);
      const float m = smax[r], sum = ssum[r], sel = ssel[r];
      const int code = scode[r];
      float p2 = 0.f;
      #pragma unroll
      for (int j=0;j<4;j++){
        const int c = wc*64 + j*16 + (lane&15);
        const float e = expf(acc[i][j][reg] - m);
        probs[grow*256 + c] = (e/sum) * sel;
        const float ev = embed[(size_t)code*256 + c];
        quant[grow*256 + c] = ev * sel;
        const float d = ev - Hn[grow*256 + c];
        p2 += d*d;
      }
      #pragma unroll
      for (int o=1;o<16;o<<=1) p2 += __shfl_xor(p2, o);
      if ((lane&15)==0) redf[wc][r] = p2;
    }
  __syncthreads();
  if (tid < 128){
    norms[bm+tid] = sqrtf(redf[0][tid]+redf[1][tid]+redf[2][tid]+redf[3][tid]);
    codef[bm+tid] = (float)scode[tid] * ssel[tid];
  }
}

// ---------------- pinv GEMM: q_inv = quant @ pinv_w + pinv_b, XCD-chunked swizzle ----------------
__global__ __launch_bounds__(512) void pinv_kernel(
    const float* __restrict__ A, const float* __restrict__ B,
    const float* __restrict__ bias, float* __restrict__ C){
  __shared__ unsigned short Ahi[4096], Alo[4096], Bhi[8192], Blo[8192];
  f32x4 acc[4][4];
  #pragma unroll
  for (int i=0;i<4;i++)
    #pragma unroll
    for (int j=0;j<4;j++) acc[i][j] = (f32x4){0.f,0.f,0.f,0.f};
  // 2048 blocks; map so each XCD owns a contiguous bm range and all 8 bn-blocks of a
  // bm land on the same XCD (A-tile L2 reuse; B is 2MB -> L2-resident).
  const int b = blockIdx.x;
  const int xcd = b & 7, seq = b >> 3;
  const int bmi = xcd*32 + (seq >> 3);
  const int bni = seq & 7;
  const int bm = bmi*128, bn = bni*256;
  mk_gemm(A + (size_t)bm*256, 256, B + bn, 2048, 256, Ahi, Alo, Bhi, Blo, acc);

  const int tid = threadIdx.x, lane = tid&63, wv = tid>>6;
  const int wr = wv>>2, wc = wv&3;
  #pragma unroll
  for (int i=0;i<4;i++){
    const int rbase = bm + wr*64 + i*16 + (lane>>4)*4;
    #pragma unroll
    for (int j=0;j<4;j++){
      const int col = bn + wc*64 + j*16 + (lane&15);
      const float bb = bias[col];
      #pragma unroll
      for (int reg=0; reg<4; reg++)
        C[(size_t)(rbase+reg)*2048 + col] = acc[i][j][reg] + bb;
    }
  }
}

// ---------------- f32 vector GEMM (codebook MLP; k-sequential, bit-stable) ----------------
template<int BM, int BN, int TM, int TN>
__global__ __launch_bounds__(256) void gemm_f32(
    const float* __restrict__ A, const float* __restrict__ B,
    const float* __restrict__ bias, float* __restrict__ C,
    int M, int N, int K){
  constexpr int BK = 16;
  constexpr int PAD = 4;
  __shared__ float As[BK][BM+PAD];
  __shared__ float Bs[BK][BN];
  const int tid = threadIdx.x;
  const int bm = blockIdx.y*BM, bn = blockIdx.x*BN;
  constexpr int NT = BN/TN;
  const int tc = tid % NT, tr = tid / NT;
  float acc[TM][TN];
  #pragma unroll
  for (int i=0;i<TM;i++)
    #pragma unroll
    for(int j=0;j<TN;j++) acc[i][j]=0.f;

  constexpr int AQ = BM*(BK/4);
  constexpr int BQ = BK*(BN/4);

  for (int k0=0;k0<K;k0+=BK){
    #pragma unroll
    for (int q=tid; q<AQ; q+=256){
      int m = q >> 2, kq = q & 3;
      const float4 v = *(const float4*)&A[(size_t)(bm+m)*K + k0 + kq*4];
      As[kq*4+0][m]=v.x; As[kq*4+1][m]=v.y; As[kq*4+2][m]=v.z; As[kq*4+3][m]=v.w;
    }
    #pragma unroll
    for (int q=tid; q<BQ; q+=256){
      int kk = q / (BN/4), nq = q % (BN/4);
      *(float4*)&Bs[kk][nq*4] = *(const float4*)&B[(size_t)(k0+kk)*N + bn + nq*4];
    }
    __syncthreads();
    #pragma unroll
    for (int kk=0;kk<BK;kk++){
      float a[TM], b[TN];
      #pragma unroll
      for (int i=0;i<TM;i++) a[i]=As[kk][tr*TM+i];
      #pragma unroll
      for (int j=0;j<TN;j++) b[j]=Bs[kk][tc*TN+j];
      #pragma unroll
      for (int i=0;i<TM;i++)
        #pragma unroll
        for (int j=0;j<TN;j++)
          acc[i][j] += a[i]*b[j];
    }
    __syncthreads();
  }
  #pragma unroll
  for (int i=0;i<TM;i++){
    const size_t row = (size_t)(bm + tr*TM + i);
    #pragma unroll
    for (int j=0;j<TN;j++){
      const size_t col = (size_t)(bn + tc*TN + j);
      float v = acc[i][j];
      if (bias) v += bias[col];
      C[row*(size_t)N + col] = v;
    }
  }
}

// ---------------- codebook first layer ----------------
__global__ __launch_bounds__(256) void cb_fc0_kernel(const float* __restrict__ w0,
                                                     const float* __restrict__ b0,
                                                     float* __restrict__ X0){
  int g = blockIdx.x*256 + threadIdx.x;
  int i = g >> 10, c = g & 1023;
  float acc = b0[c];
  #pragma unroll
  for (int j=0;j<8;j++) if ((i >> (7-j)) & 1) acc += w0[j*1024 + c];
  X0[g] = acc;
}

// ---------------- BN (batch stats over 256 rows) + ReLU (bit-identical to round 2) ----------------
__global__ __launch_bounds__(256) void bn_relu_kernel(const float* __restrict__ X,
                                                      const float* __restrict__ gma,
                                                      const float* __restrict__ bta,
                                                      float* __restrict__ Y, int C){
  const int c0 = blockIdx.x*64;
  const int t = threadIdx.x;
  const int cl = t & 63, rl = t >> 6;
  const int c = c0 + cl;
  __shared__ float red[4][64];
  __shared__ float mcol[64], vcol[64];

  float s = 0.f;
  for (int r = rl; r < 256; r += 4) s += X[r*C + c];
  red[rl][cl] = s; __syncthreads();
  if (rl==0) mcol[cl] = (red[0][cl]+red[1][cl]+red[2][cl]+red[3][cl]) * (1.0f/256.0f);
  __syncthreads();
  float m = mcol[cl];
  float s2 = 0.f;
  for (int r = rl; r < 256; r += 4){ float d = X[r*C+c]-m; s2 += d*d; }
  red[rl][cl] = s2; __syncthreads();
  if (rl==0) vcol[cl] = (red[0][cl]+red[1][cl]+red[2][cl]+red[3][cl]) * (1.0f/256.0f);
  __syncthreads();
  float scale = gma[c] * rsqrtf(vcol[cl] + 1e-5f);
  float sh = bta[c];
  for (int r = rl; r < 256; r += 4){
    float v = (X[r*C+c]-m)*scale + sh;
    Y[r*C+c] = v > 0.f ? v : 0.f;
  }
}

// ---------------- row L2-normalize for embed (bit-identical to round 2) ----------------
__global__ __launch_bounds__(256) void rownorm_kernel(const float* __restrict__ X,
                                                      float* __restrict__ Y,
                                                      float* __restrict__ YT, int nrows){
  const int n = blockIdx.x, t = threadIdx.x;
  const int lane = t & 63, wv = t >> 6;
  float x = X[(size_t)n*256 + t];
  float v = x*x;
  #pragma unroll
  for (int o=32;o;o>>=1) v += __shfl_xor(v,o);
  __shared__ float wsum[4];
  if (lane==0) wsum[wv]=v;
  __syncthreads();
  float total = wsum[0]+wsum[1]+wsum[2]+wsum[3];
  float inv = 1.0f/(sqrtf(total)+1e-6f);
  float y = x*inv;
  Y[(size_t)n*256+t] = y;
  if (YT) YT[(size_t)t*nrows + n] = y;
}

// ---------------- vq_loss = mean(norms) ----------------
__global__ __launch_bounds__(256) void loss_kernel(const float* __restrict__ norms,
                                                   float* __restrict__ outp){
  const int t = threadIdx.x;
  float s = 0.f;
  for (int i=t;i<32768;i+=256) s += norms[i];
  #pragma unroll
  for (int o=32;o;o>>=1) s += __shfl_xor(s,o);
  __shared__ float wred[4];
  if ((t&63)==0) wred[t>>6]=s;
  __syncthreads();
  if (t==0) outp[0] = (wred[0]+wred[1]+wred[2]+wred[3]) * (1.0f/32768.0f);
}

// ---------------- launch ----------------
extern "C" void kernel_launch(void* const* d_in, const int* in_sizes, int n_in,
                              void* d_out, int out_size, void* d_ws, size_t ws_size,
                              hipStream_t stream){
  const float* h_in  = (const float*)d_in[0];
  const float* temp  = (const float*)d_in[1];
  const float* proj_w= (const float*)d_in[2];
  const float* proj_b= (const float*)d_in[3];
  const float* pinv_w= (const float*)d_in[4];
  const float* pinv_b= (const float*)d_in[5];
  const float* w0 = (const float*)d_in[6];
  const float* b0 = (const float*)d_in[7];
  const float* g0 = (const float*)d_in[8];
  const float* be0= (const float*)d_in[9];
  const float* wm = (const float*)d_in[10];
  const float* bm = (const float*)d_in[11];
  const float* gm = (const float*)d_in[12];
  const float* bem= (const float*)d_in[13];
  const float* wL = (const float*)d_in[14];
  const float* bL = (const float*)d_in[15];

  float* out = (float*)d_out;
  float* q_inv  = out;                  // [32768,2048]
  float* o_code = out + 67108864;       // [32768]
  float* o_quant= out + 67141632;       // [32768,256]
  float* o_probs= out + 75530240;       // [32768,256]
  float* o_loss = out + 83918848;       // [1]

  // scratch inside q_inv region (dead before final GEMM overwrites it)
  float* Hn     = out + 0;              // [32768,256]
  float* X0b    = out + 16777216;       // [256,1024]
  float* X1b    = out + 17039360;       // [256,1024]
  float* embed  = out + 17301504;       // [256,256]
  float* embedT = out + 17367040;       // [256,256]
  float* norms  = out + 17432576;       // [32768]

  uint32_t kc0,kc1,kp0,kp1;
#if PARTITIONABLE
  threefry2x32(0u,42u, 0u,0u, kc0,kc1);
  threefry2x32(0u,42u, 0u,1u, kp0,kp1);
#else
  { uint32_t a0,b0w,a1,b1w;
    threefry2x32(0u,42u, 0u,2u, a0,b0w);
    threefry2x32(0u,42u, 1u,3u, a1,b1w);
    kc0=a0; kc1=a1; kp0=b0w; kp1=b1w; }
#endif

  // codebook MLP -> embed, embedT (f32, k-order bit-identical to round 2)
  cb_fc0_kernel<<<1024,256,0,stream>>>(w0, b0, X0b);
  bn_relu_kernel<<<16,256,0,stream>>>(X0b, g0, be0, X1b, 1024);
  for (int l=0;l<4;l++){
    gemm_f32<32,64,2,4><<<dim3(16,8),256,0,stream>>>(X1b, wm + (size_t)l*1024*1024, bm + l*1024, X0b, 256,1024,1024);
    bn_relu_kernel<<<16,256,0,stream>>>(X0b, gm + l*1024, bem + l*1024, X1b, 1024);
  }
  gemm_f32<32,64,2,4><<<dim3(4,8),256,0,stream>>>(X1b, wL, bL, X0b, 256,256,1024);
  rownorm_kernel<<<256,256,0,stream>>>(X0b, embed, embedT, 256);

  // h path: fused proj+normalize, then fused sim+sample
  proj_norm_kernel<<<256,512,0,stream>>>(h_in, proj_w, proj_b, Hn, 2048);
  sim_sample_kernel<<<256,512,0,stream>>>(Hn, embedT, embed, temp,
                                          o_probs, o_code, o_quant, norms,
                                          kc0,kc1,kp0,kp1);
  loss_kernel<<<1,256,0,stream>>>(norms, o_loss);

  // final projection (overwrites all scratch in region 0)
  pinv_kernel<<<2048,512,0,stream>>>(o_quant, pinv_w, pinv_b, q_inv);
}

// Round 4
// 811.248 us; speedup vs baseline: 1.2070x; 1.2070x over previous
//
#include <hip/hip_runtime.h>
#include <hip/hip_bf16.h>
#include <stdint.h>
#include <stddef.h>

#ifndef PARTITIONABLE
#define PARTITIONABLE 1
#endif

typedef __attribute__((ext_vector_type(8))) short short8;
typedef __attribute__((ext_vector_type(4))) short short4v;
typedef __attribute__((ext_vector_type(4))) float f32x4;

// ---------------- threefry2x32 (exact JAX) ----------------
__host__ __device__ __forceinline__ uint32_t rotl32(uint32_t x, int d){ return (x<<d)|(x>>(32-d)); }

__host__ __device__ __forceinline__ void tf4(uint32_t&x0, uint32_t&x1, int r0,int r1,int r2,int r3){
  x0+=x1; x1=rotl32(x1,r0); x1^=x0;
  x0+=x1; x1=rotl32(x1,r1); x1^=x0;
  x0+=x1; x1=rotl32(x1,r2); x1^=x0;
  x0+=x1; x1=rotl32(x1,r3); x1^=x0;
}
__host__ __device__ __forceinline__ void threefry2x32(uint32_t k0,uint32_t k1,uint32_t x0,uint32_t x1,
                                                      uint32_t&y0,uint32_t&y1){
  uint32_t ks2 = k0^k1^0x1BD11BDAu;
  x0+=k0; x1+=k1;
  tf4(x0,x1,13,15,26,6);  x0+=k1;  x1+=ks2+1u;
  tf4(x0,x1,17,29,16,24); x0+=ks2; x1+=k0+2u;
  tf4(x0,x1,13,15,26,6);  x0+=k0;  x1+=k1+3u;
  tf4(x0,x1,17,29,16,24); x0+=k1;  x1+=ks2+4u;
  tf4(x0,x1,13,15,26,6);  x0+=ks2; x1+=k0+5u;
  y0=x0; y1=x1;
}

__device__ __forceinline__ uint32_t random_bits32(uint32_t k0,uint32_t k1,uint32_t idx, uint32_t half){
#if PARTITIONABLE
  uint32_t y0,y1; threefry2x32(k0,k1, 0u, idx, y0,y1);
  (void)half;
  return y0 ^ y1;
#else
  uint32_t y0,y1;
  if (idx < half) { threefry2x32(k0,k1, idx, idx+half, y0,y1); return y0; }
  else            { threefry2x32(k0,k1, idx-half, idx, y0,y1); return y1; }
#endif
}

// ---------------- bf16 split helpers ----------------
__device__ __forceinline__ unsigned short bf16_rne(float x){
  unsigned u = __float_as_uint(x);
  unsigned r = (u + 0x7FFFu + ((u>>16)&1u)) >> 16;
  return (unsigned short)r;
}
__device__ __forceinline__ float bf16_tof(unsigned short h){
  return __uint_as_float(((unsigned)h)<<16);
}
__device__ __forceinline__ void split8(const float* src, short8& hi, short8& lo){
  #pragma unroll
  for (int e=0;e<8;e++){
    unsigned short h = bf16_rne(src[e]);
    hi[e] = (short)h;
    lo[e] = (short)bf16_rne(src[e] - bf16_tof(h));
  }
}
__device__ __forceinline__ void split4(const float* src, short4v& hi, short4v& lo){
  #pragma unroll
  for (int e=0;e<4;e++){
    unsigned short h = bf16_rne(src[e]);
    hi[e] = (short)h;
    lo[e] = (short)bf16_rne(src[e] - bf16_tof(h));
  }
}

// ---------------- Markidis split GEMM core: BMx256 tile, 512 threads ----------------
// PROD=3: hh + ah*bl + al*bh (split-2, near-f32). PROD=1: plain bf16 (hh only).
// Per-(row,col) accumulation order fixed by BK=32 sequence + product order — bit-stable
// across BM choices. acc row = wr*(BM/2)+i*16+(lane>>4)*4+reg, col = wc*64+j*16+(lane&15).
template<int BM, int PROD>
__device__ __forceinline__ void mk_gemm(const float* __restrict__ A, int lda,
                                        const float* __restrict__ B, int ldb,
                                        int K,
                                        unsigned short* Ahi, unsigned short* Alo,
                                        unsigned short* Bhi, unsigned short* Blo,
                                        f32x4 (&acc)[BM/32][4]){
  constexpr int NI = BM/32;
  const int tid = threadIdx.x;
  const int lane = tid & 63;
  const int wv = tid >> 6;            // 0..7
  const int wr = wv >> 2, wc = wv & 3;
  const int bcol = tid & 255, bkh = tid >> 8;  // 256 cols x 2 halves of 16 k
  const int swB = (bcol >> 1) & 3;

  for (int k0 = 0; k0 < K; k0 += 32){
    // ---- stage A ----
    if constexpr (BM == 128){
      const int arow = tid >> 2, aseg = tid & 3;   // 128 rows x 4 slots of 8 k
      const int swA = (arow >> 1) & 3;
      const float* pa = A + (size_t)arow*lda + k0 + aseg*8;
      float af[8];
      { float4 v0 = *(const float4*)pa; float4 v1 = *(const float4*)(pa+4);
        af[0]=v0.x; af[1]=v0.y; af[2]=v0.z; af[3]=v0.w;
        af[4]=v1.x; af[5]=v1.y; af[6]=v1.z; af[7]=v1.w; }
      short8 vh, vl; split8(af, vh, vl);
      const int s = (aseg ^ swA)*8;
      *(short8*)&Ahi[arow*32 + s] = vh;
      if constexpr (PROD == 3) *(short8*)&Alo[arow*32 + s] = vl;
    } else {                                        // BM == 64
      const int arow = tid >> 3, aseg = tid & 7;   // 64 rows x 8 half-slots of 4 k
      const int swA = (arow >> 1) & 3;
      const float* pa = A + (size_t)arow*lda + k0 + aseg*4;
      float af[4];
      { float4 v0 = *(const float4*)pa;
        af[0]=v0.x; af[1]=v0.y; af[2]=v0.z; af[3]=v0.w; }
      short4v vh, vl; split4(af, vh, vl);
      const int s = ((aseg>>1) ^ swA)*8 + (aseg&1)*4;
      *(short4v*)&Ahi[arow*32 + s] = vh;
      if constexpr (PROD == 3) *(short4v*)&Alo[arow*32 + s] = vl;
    }
    // ---- stage B: 16 f32 down a column (coalesced across lanes per instr) ----
    {
      float bf[16];
      const float* pb = B + (size_t)(k0 + bkh*16)*ldb + bcol;
      #pragma unroll
      for (int j=0;j<16;j++) bf[j] = pb[(size_t)j*ldb];
      short8 h0,l0,h1,l1; split8(bf, h0, l0); split8(bf+8, h1, l1);
      const int s0 = ((bkh*2+0)^swB)*8, s1 = ((bkh*2+1)^swB)*8;
      *(short8*)&Bhi[bcol*32 + s0] = h0;
      *(short8*)&Bhi[bcol*32 + s1] = h1;
      if constexpr (PROD == 3){
        *(short8*)&Blo[bcol*32 + s0] = l0;
        *(short8*)&Blo[bcol*32 + s1] = l1;
      }
    }
    __syncthreads();

    short8 ah[NI], al[NI], bh[4], bl[4];
    const int kg = lane >> 4;
    #pragma unroll
    for (int i=0;i<NI;i++){
      const int r = wr*(BM/2) + i*16 + (lane&15);
      const int offA = r*32 + ((kg ^ ((r>>1)&3))*8);
      ah[i] = *(const short8*)&Ahi[offA];
      if constexpr (PROD == 3) al[i] = *(const short8*)&Alo[offA];
    }
    #pragma unroll
    for (int j=0;j<4;j++){
      const int c = wc*64 + j*16 + (lane&15);
      const int offB = c*32 + ((kg ^ ((c>>1)&3))*8);
      bh[j] = *(const short8*)&Bhi[offB];
      if constexpr (PROD == 3) bl[j] = *(const short8*)&Blo[offB];
    }
    #pragma unroll
    for (int i=0;i<NI;i++)
      #pragma unroll
      for (int j=0;j<4;j++){
        acc[i][j] = __builtin_amdgcn_mfma_f32_16x16x32_bf16(ah[i], bh[j], acc[i][j], 0,0,0);
        if constexpr (PROD == 3){
          acc[i][j] = __builtin_amdgcn_mfma_f32_16x16x32_bf16(ah[i], bl[j], acc[i][j], 0,0,0);
          acc[i][j] = __builtin_amdgcn_mfma_f32_16x16x32_bf16(al[i], bh[j], acc[i][j], 0,0,0);
        }
      }
    __syncthreads();
  }
}

// ---------------- proj + rownorm fused: Hn = normalize(h_in @ proj_w + proj_b) ----------------
// BM=64 -> 512 blocks (2 wg/CU, 4 waves/SIMD) — round-3 regression fix.
__global__ __launch_bounds__(512) void proj_norm_kernel(
    const float* __restrict__ A, const float* __restrict__ B,
    const float* __restrict__ bias, float* __restrict__ Hn, int K){
  __shared__ unsigned short Ahi[2048], Alo[2048], Bhi[8192], Blo[8192];
  __shared__ float ns[4][64];
  f32x4 acc[2][4];
  #pragma unroll
  for (int i=0;i<2;i++)
    #pragma unroll
    for (int j=0;j<4;j++) acc[i][j] = (f32x4){0.f,0.f,0.f,0.f};
  const int bm = blockIdx.x * 64;
  mk_gemm<64,3>(A + (size_t)bm*K, K, B, 256, K, Ahi, Alo, Bhi, Blo, acc);

  const int tid = threadIdx.x, lane = tid&63, wv = tid>>6;
  const int wr = wv>>2, wc = wv&3;
  #pragma unroll
  for (int j=0;j<4;j++){
    const int c = wc*64 + j*16 + (lane&15);
    const float bb = bias[c];
    #pragma unroll
    for (int i=0;i<2;i++)
      #pragma unroll
      for (int reg=0;reg<4;reg++) acc[i][j][reg] += bb;
  }
  // row sum of squares (col partition/order identical to round 3 -> bit-stable)
  #pragma unroll
  for (int i=0;i<2;i++)
    #pragma unroll
    for (int reg=0;reg<4;reg++){
      float p = acc[i][0][reg]*acc[i][0][reg] + acc[i][1][reg]*acc[i][1][reg]
              + acc[i][2][reg]*acc[i][2][reg] + acc[i][3][reg]*acc[i][3][reg];
      #pragma unroll
      for (int o=1;o<16;o<<=1) p += __shfl_xor(p, o);
      if ((lane&15)==0) ns[wc][wr*32 + i*16 + (lane>>4)*4 + reg] = p;
    }
  __syncthreads();
  #pragma unroll
  for (int i=0;i<2;i++){
    const int rl = wr*32 + i*16 + (lane>>4)*4;
    #pragma unroll
    for (int reg=0;reg<4;reg++){
      const int r = rl + reg;
      const float tot = ns[0][r]+ns[1][r]+ns[2][r]+ns[3][r];
      const float inv = 1.0f/(sqrtf(tot)+1e-6f);
      const size_t grow = (size_t)(bm + r);
      #pragma unroll
      for (int j=0;j<4;j++){
        const int c = wc*64 + j*16 + (lane&15);
        Hn[grow*256 + c] = acc[i][j][reg]*inv;
      }
    }
  }
}

// ---------------- sim GEMM + softmax + gumbel-argmax + select + outputs, fused ----------------
__global__ __launch_bounds__(512) void sim_sample_kernel(
    const float* __restrict__ Hn, const float* __restrict__ embedT,
    const float* __restrict__ embed, const float* __restrict__ temp,
    float* __restrict__ probs, float* __restrict__ codef,
    float* __restrict__ quant, float* __restrict__ norms,
    uint32_t kc0, uint32_t kc1, uint32_t kp0, uint32_t kp1){
  __shared__ unsigned short Ahi[2048], Alo[2048], Bhi[8192], Blo[8192];
  __shared__ float redf[4][64];
  __shared__ int   redi[4][64];
  __shared__ float smax[64], ssum[64], ssel[64];
  __shared__ int   scode[64];
  f32x4 acc[2][4];
  #pragma unroll
  for (int i=0;i<2;i++)
    #pragma unroll
    for (int j=0;j<4;j++) acc[i][j] = (f32x4){0.f,0.f,0.f,0.f};
  const int bm = blockIdx.x * 64;
  mk_gemm<64,3>(Hn + (size_t)bm*256, 256, embedT, 256, 256, Ahi, Alo, Bhi, Blo, acc);

  const int tid = threadIdx.x, lane = tid&63, wv = tid>>6;
  const int wr = wv>>2, wc = wv&3;
  const float tv = temp[0];
  const float alpha = 1.0f/(tv*tv);
  // sim -> L (exact round-2/3 arithmetic)
  #pragma unroll
  for (int i=0;i<2;i++)
    #pragma unroll
    for (int j=0;j<4;j++)
      #pragma unroll
      for (int reg=0;reg<4;reg++){
        const float s = acc[i][j][reg];
        const float dist = -2.0f*(alpha-1.0f)*s - 2.0f*s;
        acc[i][j][reg] = -dist;
      }
  // row max
  #pragma unroll
  for (int i=0;i<2;i++)
    #pragma unroll
    for (int reg=0;reg<4;reg++){
      float m = fmaxf(fmaxf(acc[i][0][reg], acc[i][1][reg]),
                      fmaxf(acc[i][2][reg], acc[i][3][reg]));
      #pragma unroll
      for (int o=1;o<16;o<<=1) m = fmaxf(m, __shfl_xor(m, o));
      if ((lane&15)==0) redf[wc][wr*32 + i*16 + (lane>>4)*4 + reg] = m;
    }
  __syncthreads();
  if (tid < 64)
    smax[tid] = fmaxf(fmaxf(redf[0][tid], redf[1][tid]), fmaxf(redf[2][tid], redf[3][tid]));
  __syncthreads();
  // exp-sum
  #pragma unroll
  for (int i=0;i<2;i++)
    #pragma unroll
    for (int reg=0;reg<4;reg++){
      const int r = wr*32 + i*16 + (lane>>4)*4 + reg;
      const float m = smax[r];
      float p = expf(acc[i][0][reg]-m) + expf(acc[i][1][reg]-m)
              + expf(acc[i][2][reg]-m) + expf(acc[i][3][reg]-m);
      #pragma unroll
      for (int o=1;o<16;o<<=1) p += __shfl_xor(p, o);
      if ((lane&15)==0) redf[wc][r] = p;
    }
  __syncthreads();
  if (tid < 64){
    ssum[tid] = redf[0][tid]+redf[1][tid]+redf[2][tid]+redf[3][tid];
    const uint32_t pb = random_bits32(kp0,kp1,(uint32_t)(bm+tid), 16384u);
    const float pf = __uint_as_float((pb>>9) | 0x3f800000u) - 1.0f;
    ssel[tid] = (pf > 0.0f) ? 1.0f : 0.0f;
  }
  __syncthreads();
  // gumbel argmax (identical comparison order to round 3)
  #pragma unroll
  for (int i=0;i<2;i++)
    #pragma unroll
    for (int reg=0;reg<4;reg++){
      const int r = wr*32 + i*16 + (lane>>4)*4 + reg;
      const uint32_t grow = (uint32_t)(bm + r);
      float zb = -1e38f; int ib = 0x7fffffff;
      #pragma unroll
      for (int j=0;j<4;j++){
        const int c = wc*64 + j*16 + (lane&15);
        const uint32_t bits = random_bits32(kc0,kc1, grow*256u + (uint32_t)c, 4194304u);
        const float f = __uint_as_float((bits>>9) | 0x3f800000u) - 1.0f;
        const float TINY = 1.17549435082228751e-38f;
        const float u = fmaxf(TINY, f + TINY);
        const float g = -logf(-logf(u));
        const float z = acc[i][j][reg] + g;
        if (z > zb || (z == zb && c < ib)){ zb = z; ib = c; }
      }
      #pragma unroll
      for (int o=1;o<16;o<<=1){
        const float zo = __shfl_xor(zb, o); const int io = __shfl_xor(ib, o);
        if (zo > zb || (zo == zb && io < ib)){ zb = zo; ib = io; }
      }
      if ((lane&15)==0){ redf[wc][r] = zb; redi[wc][r] = ib; }
    }
  __syncthreads();
  if (tid < 64){
    float zb = redf[0][tid]; int ib = redi[0][tid];
    #pragma unroll
    for (int w=1; w<4; w++)
      if (redf[w][tid] > zb || (redf[w][tid] == zb && redi[w][tid] < ib)){
        zb = redf[w][tid]; ib = redi[w][tid];
      }
    scode[tid] = ib;
  }
  __syncthreads();
  // outputs + ||embed[code]-h|| partials
  #pragma unroll
  for (int i=0;i<2;i++)
    #pragma unroll
    for (int reg=0;reg<4;reg++){
      const int r = wr*32 + i*16 + (lane>>4)*4 + reg;
      const size_t grow = (size_t)(bm + r);
      const float m = smax[r], sum = ssum[r], sel = ssel[r];
      const int code = scode[r];
      float p2 = 0.f;
      #pragma unroll
      for (int j=0;j<4;j++){
        const int c = wc*64 + j*16 + (lane&15);
        const float e = expf(acc[i][j][reg] - m);
        probs[grow*256 + c] = (e/sum) * sel;
        const float ev = embed[(size_t)code*256 + c];
        quant[grow*256 + c] = ev * sel;
        const float d = ev - Hn[grow*256 + c];
        p2 += d*d;
      }
      #pragma unroll
      for (int o=1;o<16;o<<=1) p2 += __shfl_xor(p2, o);
      if ((lane&15)==0) redf[wc][r] = p2;
    }
  __syncthreads();
  if (tid < 64){
    norms[bm+tid] = sqrtf(redf[0][tid]+redf[1][tid]+redf[2][tid]+redf[3][tid]);
    codef[bm+tid] = (float)scode[tid] * ssel[tid];
  }
}

// ---------------- pinv GEMM: plain bf16 (1 product), XCD-chunked swizzle ----------------
__global__ __launch_bounds__(512) void pinv_kernel(
    const float* __restrict__ A, const float* __restrict__ B,
    const float* __restrict__ bias, float* __restrict__ C){
  __shared__ unsigned short Ahi[4096], Bhi[8192];
  f32x4 acc[4][4];
  #pragma unroll
  for (int i=0;i<4;i++)
    #pragma unroll
    for (int j=0;j<4;j++) acc[i][j] = (f32x4){0.f,0.f,0.f,0.f};
  const int b = blockIdx.x;
  const int xcd = b & 7, seq = b >> 3;
  const int bmi = xcd*32 + (seq >> 3);
  const int bni = seq & 7;
  const int bm = bmi*128, bn = bni*256;
  mk_gemm<128,1>(A + (size_t)bm*256, 256, B + bn, 2048, 256, Ahi, nullptr, Bhi, nullptr, acc);

  const int tid = threadIdx.x, lane = tid&63, wv = tid>>6;
  const int wr = wv>>2, wc = wv&3;
  #pragma unroll
  for (int i=0;i<4;i++){
    const int rbase = bm + wr*64 + i*16 + (lane>>4)*4;
    #pragma unroll
    for (int j=0;j<4;j++){
      const int col = bn + wc*64 + j*16 + (lane&15);
      const float bb = bias[col];
      #pragma unroll
      for (int reg=0; reg<4; reg++)
        C[(size_t)(rbase+reg)*2048 + col] = acc[i][j][reg] + bb;
    }
  }
}

// ---------------- f32 vector GEMM (codebook MLP; k-sequential, bit-stable) ----------------
template<int BM, int BN, int TM, int TN>
__global__ __launch_bounds__(256) void gemm_f32(
    const float* __restrict__ A, const float* __restrict__ B,
    const float* __restrict__ bias, float* __restrict__ C,
    int M, int N, int K){
  constexpr int BK = 16;
  constexpr int PAD = 4;
  __shared__ float As[BK][BM+PAD];
  __shared__ float Bs[BK][BN];
  const int tid = threadIdx.x;
  const int bm = blockIdx.y*BM, bn = blockIdx.x*BN;
  constexpr int NT = BN/TN;
  const int tc = tid % NT, tr = tid / NT;
  float acc[TM][TN];
  #pragma unroll
  for (int i=0;i<TM;i++)
    #pragma unroll
    for(int j=0;j<TN;j++) acc[i][j]=0.f;

  constexpr int AQ = BM*(BK/4);
  constexpr int BQ = BK*(BN/4);

  for (int k0=0;k0<K;k0+=BK){
    #pragma unroll
    for (int q=tid; q<AQ; q+=256){
      int m = q >> 2, kq = q & 3;
      const float4 v = *(const float4*)&A[(size_t)(bm+m)*K + k0 + kq*4];
      As[kq*4+0][m]=v.x; As[kq*4+1][m]=v.y; As[kq*4+2][m]=v.z; As[kq*4+3][m]=v.w;
    }
    #pragma unroll
    for (int q=tid; q<BQ; q+=256){
      int kk = q / (BN/4), nq = q % (BN/4);
      *(float4*)&Bs[kk][nq*4] = *(const float4*)&B[(size_t)(k0+kk)*N + bn + nq*4];
    }
    __syncthreads();
    #pragma unroll
    for (int kk=0;kk<BK;kk++){
      float a[TM], b[TN];
      #pragma unroll
      for (int i=0;i<TM;i++) a[i]=As[kk][tr*TM+i];
      #pragma unroll
      for (int j=0;j<TN;j++) b[j]=Bs[kk][tc*TN+j];
      #pragma unroll
      for (int i=0;i<TM;i++)
        #pragma unroll
        for (int j=0;j<TN;j++)
          acc[i][j] += a[i]*b[j];
    }
    __syncthreads();
  }
  #pragma unroll
  for (int i=0;i<TM;i++){
    const size_t row = (size_t)(bm + tr*TM + i);
    #pragma unroll
    for (int j=0;j<TN;j++){
      const size_t col = (size_t)(bn + tc*TN + j);
      float v = acc[i][j];
      if (bias) v += bias[col];
      C[row*(size_t)N + col] = v;
    }
  }
}

// ---------------- codebook first layer ----------------
__global__ __launch_bounds__(256) void cb_fc0_kernel(const float* __restrict__ w0,
                                                     const float* __restrict__ b0,
                                                     float* __restrict__ X0){
  int g = blockIdx.x*256 + threadIdx.x;
  int i = g >> 10, c = g & 1023;
  float acc = b0[c];
  #pragma unroll
  for (int j=0;j<8;j++) if ((i >> (7-j)) & 1) acc += w0[j*1024 + c];
  X0[g] = acc;
}

// ---------------- BN (batch stats over 256 rows) + ReLU ----------------
__global__ __launch_bounds__(256) void bn_relu_kernel(const float* __restrict__ X,
                                                      const float* __restrict__ gma,
                                                      const float* __restrict__ bta,
                                                      float* __restrict__ Y, int C){
  const int c0 = blockIdx.x*64;
  const int t = threadIdx.x;
  const int cl = t & 63, rl = t >> 6;
  const int c = c0 + cl;
  __shared__ float red[4][64];
  __shared__ float mcol[64], vcol[64];

  float s = 0.f;
  for (int r = rl; r < 256; r += 4) s += X[r*C + c];
  red[rl][cl] = s; __syncthreads();
  if (rl==0) mcol[cl] = (red[0][cl]+red[1][cl]+red[2][cl]+red[3][cl]) * (1.0f/256.0f);
  __syncthreads();
  float m = mcol[cl];
  float s2 = 0.f;
  for (int r = rl; r < 256; r += 4){ float d = X[r*C+c]-m; s2 += d*d; }
  red[rl][cl] = s2; __syncthreads();
  if (rl==0) vcol[cl] = (red[0][cl]+red[1][cl]+red[2][cl]+red[3][cl]) * (1.0f/256.0f);
  __syncthreads();
  float scale = gma[c] * rsqrtf(vcol[cl] + 1e-5f);
  float sh = bta[c];
  for (int r = rl; r < 256; r += 4){
    float v = (X[r*C+c]-m)*scale + sh;
    Y[r*C+c] = v > 0.f ? v : 0.f;
  }
}

// ---------------- row L2-normalize for embed ----------------
__global__ __launch_bounds__(256) void rownorm_kernel(const float* __restrict__ X,
                                                      float* __restrict__ Y,
                                                      float* __restrict__ YT, int nrows){
  const int n = blockIdx.x, t = threadIdx.x;
  const int lane = t & 63, wv = t >> 6;
  float x = X[(size_t)n*256 + t];
  float v = x*x;
  #pragma unroll
  for (int o=32;o;o>>=1) v += __shfl_xor(v,o);
  __shared__ float wsum[4];
  if (lane==0) wsum[wv]=v;
  __syncthreads();
  float total = wsum[0]+wsum[1]+wsum[2]+wsum[3];
  float inv = 1.0f/(sqrtf(total)+1e-6f);
  float y = x*inv;
  Y[(size_t)n*256+t] = y;
  if (YT) YT[(size_t)t*nrows + n] = y;
}

// ---------------- vq_loss = mean(norms) ----------------
__global__ __launch_bounds__(256) void loss_kernel(const float* __restrict__ norms,
                                                   float* __restrict__ outp){
  const int t = threadIdx.x;
  float s = 0.f;
  for (int i=t;i<32768;i+=256) s += norms[i];
  #pragma unroll
  for (int o=32;o;o>>=1) s += __shfl_xor(s,o);
  __shared__ float wred[4];
  if ((t&63)==0) wred[t>>6]=s;
  __syncthreads();
  if (t==0) outp[0] = (wred[0]+wred[1]+wred[2]+wred[3]) * (1.0f/32768.0f);
}

// ---------------- launch ----------------
extern "C" void kernel_launch(void* const* d_in, const int* in_sizes, int n_in,
                              void* d_out, int out_size, void* d_ws, size_t ws_size,
                              hipStream_t stream){
  const float* h_in  = (const float*)d_in[0];
  const float* temp  = (const float*)d_in[1];
  const float* proj_w= (const float*)d_in[2];
  const float* proj_b= (const float*)d_in[3];
  const float* pinv_w= (const float*)d_in[4];
  const float* pinv_b= (const float*)d_in[5];
  const float* w0 = (const float*)d_in[6];
  const float* b0 = (const float*)d_in[7];
  const float* g0 = (const float*)d_in[8];
  const float* be0= (const float*)d_in[9];
  const float* wm = (const float*)d_in[10];
  const float* bm = (const float*)d_in[11];
  const float* gm = (const float*)d_in[12];
  const float* bem= (const float*)d_in[13];
  const float* wL = (const float*)d_in[14];
  const float* bL = (const float*)d_in[15];

  float* out = (float*)d_out;
  float* q_inv  = out;                  // [32768,2048]
  float* o_code = out + 67108864;       // [32768]
  float* o_quant= out + 67141632;       // [32768,256]
  float* o_probs= out + 75530240;       // [32768,256]
  float* o_loss = out + 83918848;       // [1]

  // scratch inside q_inv region (dead before final GEMM overwrites it)
  float* Hn     = out + 0;              // [32768,256]
  float* X0b    = out + 16777216;       // [256,1024]
  float* X1b    = out + 17039360;       // [256,1024]
  float* embed  = out + 17301504;       // [256,256]
  float* embedT = out + 17367040;       // [256,256]
  float* norms  = out + 17432576;       // [32768]

  uint32_t kc0,kc1,kp0,kp1;
#if PARTITIONABLE
  threefry2x32(0u,42u, 0u,0u, kc0,kc1);
  threefry2x32(0u,42u, 0u,1u, kp0,kp1);
#else
  { uint32_t a0,b0w,a1,b1w;
    threefry2x32(0u,42u, 0u,2u, a0,b0w);
    threefry2x32(0u,42u, 1u,3u, a1,b1w);
    kc0=a0; kc1=a1; kp0=b0w; kp1=b1w; }
#endif

  // codebook MLP -> embed, embedT (f32, k-order bit-identical to prior rounds)
  cb_fc0_kernel<<<1024,256,0,stream>>>(w0, b0, X0b);
  bn_relu_kernel<<<16,256,0,stream>>>(X0b, g0, be0, X1b, 1024);
  for (int l=0;l<4;l++){
    gemm_f32<32,64,2,4><<<dim3(16,8),256,0,stream>>>(X1b, wm + (size_t)l*1024*1024, bm + l*1024, X0b, 256,1024,1024);
    bn_relu_kernel<<<16,256,0,stream>>>(X0b, gm + l*1024, bem + l*1024, X1b, 1024);
  }
  gemm_f32<32,64,2,4><<<dim3(4,8),256,0,stream>>>(X1b, wL, bL, X0b, 256,256,1024);
  rownorm_kernel<<<256,256,0,stream>>>(X0b, embed, embedT, 256);

  // h path: fused proj+normalize (512 blocks), then fused sim+sample (512 blocks)
  proj_norm_kernel<<<512,512,0,stream>>>(h_in, proj_w, proj_b, Hn, 2048);
  sim_sample_kernel<<<512,512,0,stream>>>(Hn, embedT, embed, temp,
                                          o_probs, o_code, o_quant, norms,
                                          kc0,kc1,kp0,kp1);
  loss_kernel<<<1,256,0,stream>>>(norms, o_loss);

  // final projection (plain bf16; overwrites all scratch in region 0)
  pinv_kernel<<<2048,512,0,stream>>>(o_quant, pinv_w, pinv_b, q_inv);
}

// Round 5
// 759.703 us; speedup vs baseline: 1.2889x; 1.0678x over previous
//
#include <hip/hip_runtime.h>
#include <hip/hip_bf16.h>
#include <stdint.h>
#include <stddef.h>

#ifndef PARTITIONABLE
#define PARTITIONABLE 1
#endif

typedef __attribute__((ext_vector_type(8))) short short8;
typedef __attribute__((ext_vector_type(4))) short short4v;
typedef __attribute__((ext_vector_type(4))) float f32x4;

// ---------------- threefry2x32 (exact JAX) ----------------
__host__ __device__ __forceinline__ uint32_t rotl32(uint32_t x, int d){ return (x<<d)|(x>>(32-d)); }

__host__ __device__ __forceinline__ void tf4(uint32_t&x0, uint32_t&x1, int r0,int r1,int r2,int r3){
  x0+=x1; x1=rotl32(x1,r0); x1^=x0;
  x0+=x1; x1=rotl32(x1,r1); x1^=x0;
  x0+=x1; x1=rotl32(x1,r2); x1^=x0;
  x0+=x1; x1=rotl32(x1,r3); x1^=x0;
}
__host__ __device__ __forceinline__ void threefry2x32(uint32_t k0,uint32_t k1,uint32_t x0,uint32_t x1,
                                                      uint32_t&y0,uint32_t&y1){
  uint32_t ks2 = k0^k1^0x1BD11BDAu;
  x0+=k0; x1+=k1;
  tf4(x0,x1,13,15,26,6);  x0+=k1;  x1+=ks2+1u;
  tf4(x0,x1,17,29,16,24); x0+=ks2; x1+=k0+2u;
  tf4(x0,x1,13,15,26,6);  x0+=k0;  x1+=k1+3u;
  tf4(x0,x1,17,29,16,24); x0+=k1;  x1+=ks2+4u;
  tf4(x0,x1,13,15,26,6);  x0+=ks2; x1+=k0+5u;
  y0=x0; y1=x1;
}

__device__ __forceinline__ uint32_t random_bits32(uint32_t k0,uint32_t k1,uint32_t idx, uint32_t half){
#if PARTITIONABLE
  uint32_t y0,y1; threefry2x32(k0,k1, 0u, idx, y0,y1);
  (void)half;
  return y0 ^ y1;
#else
  uint32_t y0,y1;
  if (idx < half) { threefry2x32(k0,k1, idx, idx+half, y0,y1); return y0; }
  else            { threefry2x32(k0,k1, idx-half, idx, y0,y1); return y1; }
#endif
}

// ---------------- bf16 split helpers ----------------
__device__ __forceinline__ unsigned short bf16_rne(float x){
  unsigned u = __float_as_uint(x);
  unsigned r = (u + 0x7FFFu + ((u>>16)&1u)) >> 16;
  return (unsigned short)r;
}
__device__ __forceinline__ float bf16_tof(unsigned short h){
  return __uint_as_float(((unsigned)h)<<16);
}
__device__ __forceinline__ void split8(const float* src, short8& hi, short8& lo){
  #pragma unroll
  for (int e=0;e<8;e++){
    unsigned short h = bf16_rne(src[e]);
    hi[e] = (short)h;
    lo[e] = (short)bf16_rne(src[e] - bf16_tof(h));
  }
}
__device__ __forceinline__ void split4(const float* src, short4v& hi, short4v& lo){
  #pragma unroll
  for (int e=0;e<4;e++){
    unsigned short h = bf16_rne(src[e]);
    hi[e] = (short)h;
    lo[e] = (short)bf16_rne(src[e] - bf16_tof(h));
  }
}

// ---------------- async global->LDS (16B/lane) ----------------
__device__ __forceinline__ void gll16(const void* g, void* l){
  __builtin_amdgcn_global_load_lds(
      (const __attribute__((address_space(1))) unsigned int*)g,
      (__attribute__((address_space(3))) unsigned int*)l, 16, 0, 0);
}

// ---------------- Markidis split-2 core, B pre-split pack, double-buffered ----------------
// smem layout (bytes): Ahi[2][2048sh]@0 (8KB), Alo@8192 (8KB), Bhi[2][8192sh]@16384 (32KB),
// Blo@49152 (32KB). Total 81920 B -> 2 blocks/CU.
// packB layout per k-step t (shorts): [hi: c*32 + s*8 + e (8192)][lo: +8192], where phys slot s
// holds logical k-group g = s ^ ((c>>1)&3) — identical image to round-4's in-kernel staging.
// Per-(row,col) accumulation order identical to round 4 -> bit-stable.
__device__ __forceinline__ void mk2_gemm(const float* __restrict__ A, int lda,
                                         const unsigned short* __restrict__ packB,
                                         int K, char* smem, f32x4 (&acc)[2][4]){
  const int tid=threadIdx.x, lane=tid&63, wv=tid>>6;
  const int wr=wv>>2, wc=wv&3;
  const int arow=tid>>3, aseg=tid&7, swA=(arow>>1)&3;
  unsigned short* Ahi=(unsigned short*)smem;
  unsigned short* Alo=(unsigned short*)(smem+8192);
  unsigned short* Bhi=(unsigned short*)(smem+16384);
  unsigned short* Blo=(unsigned short*)(smem+49152);
  const int NT=K/32;
  const int sA = arow*32 + ((aseg>>1)^swA)*8 + (aseg&1)*4;  // shorts, within buf

  // ---- prologue: stage step 0 into buf 0 ----
  {
    float4 av = *(const float4*)(A + (size_t)arow*lda + aseg*4);
    const int seg = wv*2;
    #pragma unroll
    for(int q=0;q<2;q++){
      gll16(packB + (seg+q)*512 + lane*8,        (char*)Bhi + (seg+q)*1024);
      gll16(packB + 8192 + (seg+q)*512 + lane*8, (char*)Blo + (seg+q)*1024);
    }
    float af[4]={av.x,av.y,av.z,av.w}; short4v vh,vl; split4(af,vh,vl);
    *(short4v*)&Ahi[sA]=vh; *(short4v*)&Alo[sA]=vl;
  }
  __syncthreads();

  int cur=0;
  for(int t=0;t<NT;t++){
    const bool more = (t+1<NT);
    float4 anext;
    if(more){
      anext = *(const float4*)(A + (size_t)arow*lda + (t+1)*32 + aseg*4);
      const unsigned short* src = packB + (size_t)(t+1)*16384;
      const int seg = wv*2, nb = cur^1;
      #pragma unroll
      for(int q=0;q<2;q++){
        gll16(src + (seg+q)*512 + lane*8,        (char*)Bhi + nb*16384 + (seg+q)*1024);
        gll16(src + 8192 + (seg+q)*512 + lane*8, (char*)Blo + nb*16384 + (seg+q)*1024);
      }
    }
    short8 ah[2],al[2],bh[4],bl[4];
    const int kg=lane>>4;
    #pragma unroll
    for(int i=0;i<2;i++){
      const int r = wr*32 + i*16 + (lane&15);
      const int offA = cur*2048 + r*32 + ((kg ^ ((r>>1)&3))*8);
      ah[i]=*(const short8*)&Ahi[offA]; al[i]=*(const short8*)&Alo[offA];
    }
    #pragma unroll
    for(int j=0;j<4;j++){
      const int c = wc*64 + j*16 + (lane&15);
      const int offB = cur*8192 + c*32 + ((kg ^ ((c>>1)&3))*8);
      bh[j]=*(const short8*)&Bhi[offB]; bl[j]=*(const short8*)&Blo[offB];
    }
    #pragma unroll
    for(int i=0;i<2;i++)
      #pragma unroll
      for(int j=0;j<4;j++){
        acc[i][j]=__builtin_amdgcn_mfma_f32_16x16x32_bf16(ah[i],bh[j],acc[i][j],0,0,0);
        acc[i][j]=__builtin_amdgcn_mfma_f32_16x16x32_bf16(ah[i],bl[j],acc[i][j],0,0,0);
        acc[i][j]=__builtin_amdgcn_mfma_f32_16x16x32_bf16(al[i],bh[j],acc[i][j],0,0,0);
      }
    if(more){
      float af[4]={anext.x,anext.y,anext.z,anext.w}; short4v vh,vl; split4(af,vh,vl);
      const int nb=cur^1;
      *(short4v*)&Ahi[nb*2048 + sA]=vh; *(short4v*)&Alo[nb*2048 + sA]=vl;
    }
    __syncthreads();
    cur^=1;
  }
}

// ---------------- pack proj_w -> pre-split LDS-image layout ----------------
// grid: (K/32)*4 blocks x 256 thr. Block b: t=b>>2, s=b&3; thread = col c.
__global__ __launch_bounds__(256) void pack_w_kernel(const float* __restrict__ W,
                                                     unsigned short* __restrict__ pack){
  const int t = blockIdx.x>>2, s = blockIdx.x&3, c = threadIdx.x;
  const int g = s ^ ((c>>1)&3);
  const float* p = W + (size_t)(t*32 + g*8)*256 + c;
  float bf[8];
  #pragma unroll
  for(int e=0;e<8;e++) bf[e]=p[(size_t)e*256];
  short8 h,l; split8(bf,h,l);
  unsigned short* dst = pack + (size_t)t*16384 + c*32 + s*8;
  *(short8*)dst = h;
  *(short8*)(dst+8192) = l;
}

// ---------------- proj + rownorm fused ----------------
__global__ __launch_bounds__(512,4) void proj_norm_kernel(
    const float* __restrict__ A, const unsigned short* __restrict__ packW,
    const float* __restrict__ bias, float* __restrict__ Hn, int K){
  __shared__ char smem[81920];
  f32x4 acc[2][4];
  #pragma unroll
  for (int i=0;i<2;i++)
    #pragma unroll
    for (int j=0;j<4;j++) acc[i][j] = (f32x4){0.f,0.f,0.f,0.f};
  const int bm = blockIdx.x * 64;
  mk2_gemm(A + (size_t)bm*K, K, packW, K, smem, acc);

  const int tid = threadIdx.x, lane = tid&63, wv = tid>>6;
  const int wr = wv>>2, wc = wv&3;
  float* ns = (float*)smem;  // [4][64], aliased post-loop
  #pragma unroll
  for (int j=0;j<4;j++){
    const int c = wc*64 + j*16 + (lane&15);
    const float bb = bias[c];
    #pragma unroll
    for (int i=0;i<2;i++)
      #pragma unroll
      for (int reg=0;reg<4;reg++) acc[i][j][reg] += bb;
  }
  #pragma unroll
  for (int i=0;i<2;i++)
    #pragma unroll
    for (int reg=0;reg<4;reg++){
      float p = acc[i][0][reg]*acc[i][0][reg] + acc[i][1][reg]*acc[i][1][reg]
              + acc[i][2][reg]*acc[i][2][reg] + acc[i][3][reg]*acc[i][3][reg];
      #pragma unroll
      for (int o=1;o<16;o<<=1) p += __shfl_xor(p, o);
      if ((lane&15)==0) ns[wc*64 + wr*32 + i*16 + (lane>>4)*4 + reg] = p;
    }
  __syncthreads();
  #pragma unroll
  for (int i=0;i<2;i++){
    const int rl = wr*32 + i*16 + (lane>>4)*4;
    #pragma unroll
    for (int reg=0;reg<4;reg++){
      const int r = rl + reg;
      const float tot = ns[0*64+r]+ns[1*64+r]+ns[2*64+r]+ns[3*64+r];
      const float inv = 1.0f/(sqrtf(tot)+1e-6f);
      const size_t grow = (size_t)(bm + r);
      #pragma unroll
      for (int j=0;j<4;j++){
        const int c = wc*64 + j*16 + (lane&15);
        Hn[grow*256 + c] = acc[i][j][reg]*inv;
      }
    }
  }
}

// ---------------- sim GEMM + softmax + gumbel-argmax + select + outputs, fused ----------------
__global__ __launch_bounds__(512) void sim_sample_kernel(
    const float* __restrict__ Hn, const unsigned short* __restrict__ packE,
    const float* __restrict__ embed, const float* __restrict__ temp,
    float* __restrict__ probs, float* __restrict__ codef,
    float* __restrict__ quant, float* __restrict__ norms,
    int* __restrict__ codes_g, float* __restrict__ sels_g,
    uint32_t kc0, uint32_t kc1, uint32_t kp0, uint32_t kp1){
  __shared__ char smem[81920];
  f32x4 acc[2][4];
  #pragma unroll
  for (int i=0;i<2;i++)
    #pragma unroll
    for (int j=0;j<4;j++) acc[i][j] = (f32x4){0.f,0.f,0.f,0.f};
  const int bm = blockIdx.x * 64;
  mk2_gemm(Hn + (size_t)bm*256, 256, packE, 256, smem, acc);

  // epilogue scratch aliased onto smem (loop done, all barriers passed)
  float* redf = (float*)smem;            // [4][64]
  int*   redi = (int*)(smem+1024);       // [4][64]
  float* smax = (float*)(smem+2048);     // [64]
  float* ssum = (float*)(smem+2304);     // [64]
  float* ssel = (float*)(smem+2560);     // [64]
  int*  scode = (int*)(smem+2816);       // [64]

  const int tid = threadIdx.x, lane = tid&63, wv = tid>>6;
  const int wr = wv>>2, wc = wv&3;
  const float tv = temp[0];
  const float alpha = 1.0f/(tv*tv);
  #pragma unroll
  for (int i=0;i<2;i++)
    #pragma unroll
    for (int j=0;j<4;j++)
      #pragma unroll
      for (int reg=0;reg<4;reg++){
        const float s = acc[i][j][reg];
        const float dist = -2.0f*(alpha-1.0f)*s - 2.0f*s;
        acc[i][j][reg] = -dist;
      }
  // row max
  #pragma unroll
  for (int i=0;i<2;i++)
    #pragma unroll
    for (int reg=0;reg<4;reg++){
      float m = fmaxf(fmaxf(acc[i][0][reg], acc[i][1][reg]),
                      fmaxf(acc[i][2][reg], acc[i][3][reg]));
      #pragma unroll
      for (int o=1;o<16;o<<=1) m = fmaxf(m, __shfl_xor(m, o));
      if ((lane&15)==0) redf[wc*64 + wr*32 + i*16 + (lane>>4)*4 + reg] = m;
    }
  __syncthreads();
  if (tid < 64)
    smax[tid] = fmaxf(fmaxf(redf[0*64+tid], redf[1*64+tid]), fmaxf(redf[2*64+tid], redf[3*64+tid]));
  __syncthreads();
  // exp-sum
  #pragma unroll
  for (int i=0;i<2;i++)
    #pragma unroll
    for (int reg=0;reg<4;reg++){
      const int r = wr*32 + i*16 + (lane>>4)*4 + reg;
      const float m = smax[r];
      float p = expf(acc[i][0][reg]-m) + expf(acc[i][1][reg]-m)
              + expf(acc[i][2][reg]-m) + expf(acc[i][3][reg]-m);
      #pragma unroll
      for (int o=1;o<16;o<<=1) p += __shfl_xor(p, o);
      if ((lane&15)==0) redf[wc*64 + r] = p;
    }
  __syncthreads();
  if (tid < 64){
    ssum[tid] = redf[0*64+tid]+redf[1*64+tid]+redf[2*64+tid]+redf[3*64+tid];
    const uint32_t pb = random_bits32(kp0,kp1,(uint32_t)(bm+tid), 16384u);
    const float pf = __uint_as_float((pb>>9) | 0x3f800000u) - 1.0f;
    ssel[tid] = (pf > 0.0f) ? 1.0f : 0.0f;
  }
  __syncthreads();
  // gumbel argmax (identical comparison order to round 4)
  #pragma unroll
  for (int i=0;i<2;i++)
    #pragma unroll
    for (int reg=0;reg<4;reg++){
      const int r = wr*32 + i*16 + (lane>>4)*4 + reg;
      const uint32_t grow = (uint32_t)(bm + r);
      float zb = -1e38f; int ib = 0x7fffffff;
      #pragma unroll
      for (int j=0;j<4;j++){
        const int c = wc*64 + j*16 + (lane&15);
        const uint32_t bits = random_bits32(kc0,kc1, grow*256u + (uint32_t)c, 4194304u);
        const float f = __uint_as_float((bits>>9) | 0x3f800000u) - 1.0f;
        const float TINY = 1.17549435082228751e-38f;
        const float u = fmaxf(TINY, f + TINY);
        const float g = -logf(-logf(u));
        const float z = acc[i][j][reg] + g;
        if (z > zb || (z == zb && c < ib)){ zb = z; ib = c; }
      }
      #pragma unroll
      for (int o=1;o<16;o<<=1){
        const float zo = __shfl_xor(zb, o); const int io = __shfl_xor(ib, o);
        if (zo > zb || (zo == zb && io < ib)){ zb = zo; ib = io; }
      }
      if ((lane&15)==0){ redf[wc*64 + r] = zb; redi[wc*64 + r] = ib; }
    }
  __syncthreads();
  if (tid < 64){
    float zb = redf[0*64+tid]; int ib = redi[0*64+tid];
    #pragma unroll
    for (int w=1; w<4; w++)
      if (redf[w*64+tid] > zb || (redf[w*64+tid] == zb && redi[w*64+tid] < ib)){
        zb = redf[w*64+tid]; ib = redi[w*64+tid];
      }
    scode[tid] = ib;
  }
  __syncthreads();
  // outputs + ||embed[code]-h|| partials
  #pragma unroll
  for (int i=0;i<2;i++)
    #pragma unroll
    for (int reg=0;reg<4;reg++){
      const int r = wr*32 + i*16 + (lane>>4)*4 + reg;
      const size_t grow = (size_t)(bm + r);
      const float m = smax[r], sum = ssum[r], sel = ssel[r];
      const int code = scode[r];
      float p2 = 0.f;
      #pragma unroll
      for (int j=0;j<4;j++){
        const int c = wc*64 + j*16 + (lane&15);
        const float e = expf(acc[i][j][reg] - m);
        probs[grow*256 + c] = (e/sum) * sel;
        const float ev = embed[(size_t)code*256 + c];
        quant[grow*256 + c] = ev * sel;
        const float d = ev - Hn[grow*256 + c];
        p2 += d*d;
      }
      #pragma unroll
      for (int o=1;o<16;o<<=1) p2 += __shfl_xor(p2, o);
      if ((lane&15)==0) redf[wc*64 + r] = p2;
    }
  __syncthreads();
  if (tid < 64){
    norms[bm+tid] = sqrtf(redf[0*64+tid]+redf[1*64+tid]+redf[2*64+tid]+redf[3*64+tid]);
    codef[bm+tid] = (float)scode[tid] * ssel[tid];
    codes_g[bm+tid] = scode[tid];
    sels_g[bm+tid] = ssel[tid];
  }
}

// ---------------- gather: q_inv[n] = sel ? Epp[code] : pinv_b ----------------
__global__ __launch_bounds__(256) void gather_kernel(
    const float* __restrict__ Epp, const float* __restrict__ pinv_b,
    const int* __restrict__ codes, const float* __restrict__ sels,
    float* __restrict__ q_inv){
  const int n = blockIdx.x;
  const float sel = sels[n];
  const int c = codes[n];
  const float4* src = (const float4*)((sel != 0.0f) ? (Epp + (size_t)c*2048) : pinv_b);
  float4* dst = (float4*)(q_inv + (size_t)n*2048);
  dst[threadIdx.x]       = src[threadIdx.x];
  dst[threadIdx.x + 256] = src[threadIdx.x + 256];
}

// ---------------- f32 vector GEMM (codebook MLP + Epp; k-sequential, bit-stable) ----------------
template<int BM, int BN, int TM, int TN>
__global__ __launch_bounds__(256) void gemm_f32(
    const float* __restrict__ A, const float* __restrict__ B,
    const float* __restrict__ bias, float* __restrict__ C,
    int M, int N, int K){
  constexpr int BK = 16;
  constexpr int PAD = 4;
  __shared__ float As[BK][BM+PAD];
  __shared__ float Bs[BK][BN];
  const int tid = threadIdx.x;
  const int bm = blockIdx.y*BM, bn = blockIdx.x*BN;
  constexpr int NT = BN/TN;
  const int tc = tid % NT, tr = tid / NT;
  float acc[TM][TN];
  #pragma unroll
  for (int i=0;i<TM;i++)
    #pragma unroll
    for(int j=0;j<TN;j++) acc[i][j]=0.f;

  constexpr int AQ = BM*(BK/4);
  constexpr int BQ = BK*(BN/4);

  for (int k0=0;k0<K;k0+=BK){
    #pragma unroll
    for (int q=tid; q<AQ; q+=256){
      int m = q >> 2, kq = q & 3;
      const float4 v = *(const float4*)&A[(size_t)(bm+m)*K + k0 + kq*4];
      As[kq*4+0][m]=v.x; As[kq*4+1][m]=v.y; As[kq*4+2][m]=v.z; As[kq*4+3][m]=v.w;
    }
    #pragma unroll
    for (int q=tid; q<BQ; q+=256){
      int kk = q / (BN/4), nq = q % (BN/4);
      *(float4*)&Bs[kk][nq*4] = *(const float4*)&B[(size_t)(k0+kk)*N + bn + nq*4];
    }
    __syncthreads();
    #pragma unroll
    for (int kk=0;kk<BK;kk++){
      float a[TM], b[TN];
      #pragma unroll
      for (int i=0;i<TM;i++) a[i]=As[kk][tr*TM+i];
      #pragma unroll
      for (int j=0;j<TN;j++) b[j]=Bs[kk][tc*TN+j];
      #pragma unroll
      for (int i=0;i<TM;i++)
        #pragma unroll
        for (int j=0;j<TN;j++)
          acc[i][j] += a[i]*b[j];
    }
    __syncthreads();
  }
  #pragma unroll
  for (int i=0;i<TM;i++){
    const size_t row = (size_t)(bm + tr*TM + i);
    #pragma unroll
    for (int j=0;j<TN;j++){
      const size_t col = (size_t)(bn + tc*TN + j);
      float v = acc[i][j];
      if (bias) v += bias[col];
      C[row*(size_t)N + col] = v;
    }
  }
}

// ---------------- codebook first layer ----------------
__global__ __launch_bounds__(256) void cb_fc0_kernel(const float* __restrict__ w0,
                                                     const float* __restrict__ b0,
                                                     float* __restrict__ X0){
  int g = blockIdx.x*256 + threadIdx.x;
  int i = g >> 10, c = g & 1023;
  float acc = b0[c];
  #pragma unroll
  for (int j=0;j<8;j++) if ((i >> (7-j)) & 1) acc += w0[j*1024 + c];
  X0[g] = acc;
}

// ---------------- BN (batch stats over 256 rows) + ReLU ----------------
__global__ __launch_bounds__(256) void bn_relu_kernel(const float* __restrict__ X,
                                                      const float* __restrict__ gma,
                                                      const float* __restrict__ bta,
                                                      float* __restrict__ Y, int C){
  const int c0 = blockIdx.x*64;
  const int t = threadIdx.x;
  const int cl = t & 63, rl = t >> 6;
  const int c = c0 + cl;
  __shared__ float red[4][64];
  __shared__ float mcol[64], vcol[64];

  float s = 0.f;
  for (int r = rl; r < 256; r += 4) s += X[r*C + c];
  red[rl][cl] = s; __syncthreads();
  if (rl==0) mcol[cl] = (red[0][cl]+red[1][cl]+red[2][cl]+red[3][cl]) * (1.0f/256.0f);
  __syncthreads();
  float m = mcol[cl];
  float s2 = 0.f;
  for (int r = rl; r < 256; r += 4){ float d = X[r*C+c]-m; s2 += d*d; }
  red[rl][cl] = s2; __syncthreads();
  if (rl==0) vcol[cl] = (red[0][cl]+red[1][cl]+red[2][cl]+red[3][cl]) * (1.0f/256.0f);
  __syncthreads();
  float scale = gma[c] * rsqrtf(vcol[cl] + 1e-5f);
  float sh = bta[c];
  for (int r = rl; r < 256; r += 4){
    float v = (X[r*C+c]-m)*scale + sh;
    Y[r*C+c] = v > 0.f ? v : 0.f;
  }
}

// ---------------- row L2-normalize for embed + pack for sim B ----------------
__global__ __launch_bounds__(256) void rownorm_pack_kernel(const float* __restrict__ X,
                                                           float* __restrict__ Y,
                                                           unsigned short* __restrict__ pack){
  const int n = blockIdx.x, t = threadIdx.x;
  const int lane = t & 63, wv = t >> 6;
  float x = X[(size_t)n*256 + t];
  float v = x*x;
  #pragma unroll
  for (int o=32;o;o>>=1) v += __shfl_xor(v,o);
  __shared__ float wsum[4];
  if (lane==0) wsum[wv]=v;
  __syncthreads();
  float total = wsum[0]+wsum[1]+wsum[2]+wsum[3];
  float inv = 1.0f/(sqrtf(total)+1e-6f);
  float y = x*inv;
  Y[(size_t)n*256+t] = y;
  // pack: B[k][c] = embed[c][k]; here c=n, k=t — same bf16_rne values as round-4 staging
  unsigned short h = bf16_rne(y);
  unsigned short l = bf16_rne(y - bf16_tof(h));
  const int tt=t>>5, kk=t&31, g=kk>>3, e=kk&7, s=g^((n>>1)&3);
  unsigned short* d = pack + (size_t)tt*16384 + n*32 + s*8 + e;
  d[0] = h; d[8192] = l;
}

// ---------------- vq_loss = mean(norms) ----------------
__global__ __launch_bounds__(256) void loss_kernel(const float* __restrict__ norms,
                                                   float* __restrict__ outp){
  const int t = threadIdx.x;
  float s = 0.f;
  for (int i=t;i<32768;i+=256) s += norms[i];
  #pragma unroll
  for (int o=32;o;o>>=1) s += __shfl_xor(s,o);
  __shared__ float wred[4];
  if ((t&63)==0) wred[t>>6]=s;
  __syncthreads();
  if (t==0) outp[0] = (wred[0]+wred[1]+wred[2]+wred[3]) * (1.0f/32768.0f);
}

// ---------------- launch ----------------
extern "C" void kernel_launch(void* const* d_in, const int* in_sizes, int n_in,
                              void* d_out, int out_size, void* d_ws, size_t ws_size,
                              hipStream_t stream){
  const float* h_in  = (const float*)d_in[0];
  const float* temp  = (const float*)d_in[1];
  const float* proj_w= (const float*)d_in[2];
  const float* proj_b= (const float*)d_in[3];
  const float* pinv_w= (const float*)d_in[4];
  const float* pinv_b= (const float*)d_in[5];
  const float* w0 = (const float*)d_in[6];
  const float* b0 = (const float*)d_in[7];
  const float* g0 = (const float*)d_in[8];
  const float* be0= (const float*)d_in[9];
  const float* wm = (const float*)d_in[10];
  const float* bm = (const float*)d_in[11];
  const float* gm = (const float*)d_in[12];
  const float* bem= (const float*)d_in[13];
  const float* wL = (const float*)d_in[14];
  const float* bL = (const float*)d_in[15];

  float* out = (float*)d_out;
  float* q_inv  = out;                  // [32768,2048]
  float* o_code = out + 67108864;       // [32768]
  float* o_quant= out + 67141632;       // [32768,256]
  float* o_probs= out + 75530240;       // [32768,256]
  float* o_loss = out + 83918848;       // [1]

  // scratch in d_ws (~41 MB used; ws observed ~1.3 GB)
  float* ws = (float*)d_ws;
  float* Hn     = ws + 0;               // [32768,256]
  float* X0b    = ws + 8388608;         // [256,1024]
  float* X1b    = ws + 8650752;         // [256,1024]
  float* embed  = ws + 8912896;         // [256,256]
  float* norms  = ws + 8978432;         // [32768]
  float* sels   = ws + 9011200;         // [32768]
  int*   codes  = (int*)(ws + 9043968); // [32768]
  float* Epp    = ws + 9076736;         // [256,2048]
  unsigned short* packW = (unsigned short*)(ws + 9601024);   // 64 steps x 16384 shorts
  unsigned short* packE = (unsigned short*)(ws + 10125312);  // 8 steps x 16384 shorts

  uint32_t kc0,kc1,kp0,kp1;
#if PARTITIONABLE
  threefry2x32(0u,42u, 0u,0u, kc0,kc1);
  threefry2x32(0u,42u, 0u,1u, kp0,kp1);
#else
  { uint32_t a0,b0w,a1,b1w;
    threefry2x32(0u,42u, 0u,2u, a0,b0w);
    threefry2x32(0u,42u, 1u,3u, a1,b1w);
    kc0=a0; kc1=a1; kp0=b0w; kp1=b1w; }
#endif

  // pre-split proj_w into the LDS-image pack (bit-identical values to in-kernel split)
  pack_w_kernel<<<256,256,0,stream>>>(proj_w, packW);

  // codebook MLP -> embed + packE (f32, k-order bit-identical to prior rounds)
  cb_fc0_kernel<<<1024,256,0,stream>>>(w0, b0, X0b);
  bn_relu_kernel<<<16,256,0,stream>>>(X0b, g0, be0, X1b, 1024);
  for (int l=0;l<4;l++){
    gemm_f32<32,64,2,4><<<dim3(16,8),256,0,stream>>>(X1b, wm + (size_t)l*1024*1024, bm + l*1024, X0b, 256,1024,1024);
    bn_relu_kernel<<<16,256,0,stream>>>(X0b, gm + l*1024, bem + l*1024, X1b, 1024);
  }
  gemm_f32<32,64,2,4><<<dim3(4,8),256,0,stream>>>(X1b, wL, bL, X0b, 256,256,1024);
  rownorm_pack_kernel<<<256,256,0,stream>>>(X0b, embed, packE);

  // E'' = embed @ pinv_w + pinv_b (f32, tiny)
  gemm_f32<32,64,2,4><<<dim3(32,8),256,0,stream>>>(embed, pinv_w, pinv_b, Epp, 256,2048,256);

  // h path: fused proj+normalize, then fused sim+sample (logit bits frozen vs round 4)
  proj_norm_kernel<<<512,512,0,stream>>>(h_in, packW, proj_b, Hn, 2048);
  sim_sample_kernel<<<512,512,0,stream>>>(Hn, packE, embed, temp,
                                          o_probs, o_code, o_quant, norms,
                                          codes, sels, kc0,kc1,kp0,kp1);
  loss_kernel<<<1,256,0,stream>>>(norms, o_loss);

  // final projection as a row gather from E''
  gather_kernel<<<32768,256,0,stream>>>(Epp, pinv_b, codes, sels, q_inv);
}